// Round 6
// baseline (65592.578 us; speedup 1.0000x reference)
//
#include <hip/hip_runtime.h>

#define DEV __device__ __forceinline__

typedef __attribute__((ext_vector_type(8))) short short8;   // 8 bf16 = 4 VGPR
typedef __attribute__((ext_vector_type(4))) float f32x4;
typedef __attribute__((ext_vector_type(4))) unsigned short us4;

namespace {
constexpr int NWG = 256, NTH = 1024;
constexpr int Bc = 32, TENC = 512, TDECc = 512, Dc = 512, MELc = 80;

// ---- mutable (memset-zeroed) region ----
constexpr size_t OFF_S    = 640;                                 // [2][32] softmax denom
constexpr size_t OFF_W    = OFF_S + 64;                          // [2][32][512] exp(e)
constexpr size_t OFF_ACUM = OFF_W    + (size_t)2 * Bc * TENC;    // [2][32][512]
constexpr size_t OFF_CTXT = OFF_ACUM + (size_t)2 * Bc * TENC;    // [2][512][32] unnormalized ctx^T
constexpr size_t OFF_HATT = OFF_CTXT + (size_t)2 * Dc * Bc;      // [2][512][32]
constexpr size_t OFF_HDEC = OFF_HATT + (size_t)2 * Dc * Bc;      // [2][512][32]
constexpr size_t OFF_CATT = OFF_HDEC + (size_t)2 * Dc * Bc;      // [512][32]
constexpr size_t OFF_CDEC = OFF_CATT + (size_t)Dc * Bc;          // [512][32]
constexpr size_t OFF_Q    = OFF_CDEC + (size_t)Dc * Bc;          // [32][512]
constexpr size_t ZERO_END = OFF_Q    + (size_t)Bc * Dc;
// ---- read-only after INIT / per-step rewritten ----
constexpr size_t OFF_MPROJ = (ZERO_END + 255) & ~(size_t)255;    // fp32 [32][512(t)][512(d)] (init->LDS only)
constexpr size_t OFF_WA2   = OFF_MPROJ + (size_t)Bc * TENC * Dc; // att A-frags [128][70][64][8] bf16 (hi35|lo35)
constexpr size_t OFF_WD2   = OFF_WA2 + (size_t)128*70*64*4;      // dec A-frags [128][96][64][8] (hi48|lo48)
constexpr size_t OFF_WL2   = OFF_WD2 + (size_t)128*96*64*4;      // conv A-frags [32][4][64][8] (hi2|lo2)
constexpr size_t OFF_XSA   = OFF_WL2 + (size_t)32*4*64*4;        // att B-frags [70][2][64][8] (hi35|lo35)
constexpr size_t OFF_XSD   = OFF_XSA + (size_t)70*2*64*4;        // dec B-frags [96][2][64][8]
constexpr size_t OFF_WQT   = OFF_XSD + (size_t)96*2*64*4;        // [512][512] fp32
constexpr size_t OFF_WMELT = OFF_WQT + (size_t)Dc*Dc;            // [512][80]
constexpr size_t OFF_MELT  = OFF_WMELT + (size_t)Dc*MELc;        // [512][80][32]
constexpr size_t OFF_BA    = OFF_MELT + (size_t)TDECc*MELc*Bc;   // [2048] interleaved c=u*4+ty
constexpr size_t OFF_BD    = OFF_BA + 2048;                      // [2048]
} // namespace

// device-coherent (L3-direct) accessors for mutable cross-WG state
DEV float ldg_(const float* p) { return __hip_atomic_load((float*)p, __ATOMIC_RELAXED, __HIP_MEMORY_SCOPE_AGENT); }
DEV void  stg_(float* p, float x) { __hip_atomic_store(p, x, __ATOMIC_RELAXED, __HIP_MEMORY_SCOPE_AGENT); }
DEV unsigned ldgu_(const unsigned* p) { return __hip_atomic_load((unsigned*)p, __ATOMIC_RELAXED, __HIP_MEMORY_SCOPE_AGENT); }
DEV void  stgu_(unsigned* p, unsigned x) { __hip_atomic_store(p, x, __ATOMIC_RELAXED, __HIP_MEMORY_SCOPE_AGENT); }
DEV void  atadd_(float* p, float x) { (void)__hip_atomic_fetch_add(p, x, __ATOMIC_RELAXED, __HIP_MEMORY_SCOPE_AGENT); }
DEV float sigf(float x) { return 1.0f / (1.0f + __expf(-x)); }
DEV float tanhf2(float x) { return 1.0f - 2.0f / (__expf(2.0f * x) + 1.0f); }
DEV unsigned short bfh(float x) { union { float f; unsigned u; } v; v.f = x; unsigned r = v.u + 0x7FFF + ((v.u >> 16) & 1); return (unsigned short)(r >> 16); }
DEV float bf2f(unsigned short h) { union { unsigned u; float f; } v; v.u = (unsigned)h << 16; return v.f; }

union PK8 { unsigned short us[8]; short8 s8; unsigned u[4]; };

DEV void store_pk(unsigned short* dst, const PK8& pk) {
  unsigned* d = (unsigned*)dst;
#pragma unroll
  for (int i = 0; i < 4; ++i) stgu_(d + i, pk.u[i]);
}

struct __attribute__((aligned(16))) Lds {
  unsigned short mp[64][520];   // bf16 m_proj slice [t][d], +8 pad vs bank conflicts
  unsigned short en[64][520];   // bf16 enc slice [t][d]
  union {
    struct __attribute__((aligned(16))) {
      unsigned short win[4][4][64][8];  // conv B frags [nt][ks(hi2|lo2)][lane][8]
      float q[512], v[512];
      float ain[96], acin[96];
      float ered[16][64];
      float we[64];
    } t1;                                              // 25,600 B
    struct __attribute__((aligned(16))) { float red[8][2][64][4]; } gg;  // 16,384 B
    struct { float tw[32][33], ta[32][33]; } init;     // 8,448 B
    struct { float h[512]; float part[256][4]; float sp[32][33]; } qm;   // 10,368 B
  } u;
};

__global__ __launch_bounds__(NTH, 4) void decoder_persist(
    const float* __restrict__ enc, const float* __restrict__ mel_in,
    const float* __restrict__ Wih_att, const float* __restrict__ Whh_att, const float* __restrict__ b_att,
    const float* __restrict__ Wih_dec, const float* __restrict__ Whh_dec, const float* __restrict__ b_dec,
    const float* __restrict__ Wq, const float* __restrict__ Wm, const float* __restrict__ Wloc,
    const float* __restrict__ v, const float* __restrict__ Wmel, const float* __restrict__ bmel,
    const float* __restrict__ Wstop, const float* __restrict__ bstop,
    float* __restrict__ out, float* __restrict__ ws)
{
  const int wg = blockIdx.x, tid = threadIdx.x;
  extern __shared__ __align__(16) char smem_raw[];
  Lds& sh = *(Lds*)smem_raw;

  unsigned int* bar = (unsigned int*)(ws);           // gen @0; cells @64+(p*8+i)*32
  float* S  = ws + OFF_S;   float* Wb = ws + OFF_W;   float* AC = ws + OFF_ACUM;
  float* CT = ws + OFF_CTXT; float* HA = ws + OFF_HATT; float* HD = ws + OFF_HDEC;
  float* CA = ws + OFF_CATT; float* CD = ws + OFF_CDEC; float* Q  = ws + OFF_Q;
  float* MP = ws + OFF_MPROJ;
  unsigned short* WA2 = (unsigned short*)(ws + OFF_WA2);
  unsigned short* WD2 = (unsigned short*)(ws + OFF_WD2);
  unsigned short* WL2 = (unsigned short*)(ws + OFF_WL2);
  unsigned short* XSA = (unsigned short*)(ws + OFF_XSA);
  unsigned short* XSD = (unsigned short*)(ws + OFF_XSD);
  float* WQT = ws + OFF_WQT; float* WMT = ws + OFF_WMELT; float* MT = ws + OFF_MELT;
  float* BA = ws + OFF_BA;  float* BD = ws + OFF_BD;

  // ---- grid barrier: 8 padded arrival cells (parity-duplexed) + master poll ----
  auto gbar = [&]() {
    __syncthreads();
    if (tid == 0) {
      unsigned g = __hip_atomic_load(&bar[0], __ATOMIC_RELAXED, __HIP_MEMORY_SCOPE_AGENT);
      unsigned p = g & 1u;
      (void)__hip_atomic_fetch_add(&bar[64 + (p * 8 + (wg & 7)) * 32], 1u, __ATOMIC_RELEASE, __HIP_MEMORY_SCOPE_AGENT);
      if (wg == 0) {
        for (;;) {
          unsigned s = 0;
#pragma unroll
          for (int i = 0; i < 8; ++i)
            s += __hip_atomic_load(&bar[64 + (p * 8 + i) * 32], __ATOMIC_RELAXED, __HIP_MEMORY_SCOPE_AGENT);
          if (s == (unsigned)NWG) break;
          __builtin_amdgcn_s_sleep(2);
        }
#pragma unroll
        for (int i = 0; i < 8; ++i)
          __hip_atomic_store(&bar[64 + (p * 8 + i) * 32], 0u, __ATOMIC_RELAXED, __HIP_MEMORY_SCOPE_AGENT);
        (void)__hip_atomic_fetch_add(&bar[0], 1u, __ATOMIC_RELEASE, __HIP_MEMORY_SCOPE_AGENT);
      } else {
        while (__hip_atomic_load(&bar[0], __ATOMIC_RELAXED, __HIP_MEMORY_SCOPE_AGENT) == g)
          __builtin_amdgcn_s_sleep(4);
      }
    }
    __syncthreads();
  };

  // ================= INIT =================
  {
    for (int k = wg; k < Dc; k += NWG)
      for (int d = tid; d < Dc; d += NTH) stg_(WQT + (size_t)k * Dc + d, Wq[(size_t)d * Dc + k]);
    if (wg == 0)
      for (int i = tid; i < Dc * MELc; i += NTH) { int k = i / MELc, m = i % MELc; stg_(WMT + (size_t)k * MELc + m, Wmel[(size_t)m * Dc + k]); }
    if (wg == 1)
      for (int c = tid; c < 2048; c += NTH) { int u = c >> 2, ty = c & 3; stg_(BA + c, b_att[ty * Dc + u]); stg_(BD + c, b_dec[ty * Dc + u]); }
    if (wg == 2 && tid < Bc) stg_(S + 32 + tid, 1.0f);
    for (int t = wg; t < TDECc; t += NWG)
      for (int i = tid; i < MELc * Bc; i += NTH) {
        int m = i >> 5, b = i & 31;
        stg_(MT + (size_t)t * MELc * Bc + m * Bc + b, mel_in[(size_t)b * TDECc * MELc + (size_t)t * MELc + m]);
      }
    // att A-frags: groups [Ah(35 ks); Al(35 ks)], K=1104 pad 1120
    for (size_t id = (size_t)wg * NTH + tid; id < (size_t)128 * 70 * 64; id += (size_t)NWG * NTH) {
      int l = id & 63; size_t r = id >> 6; int ks = (int)(r % 70); int m = (int)(r / 70);
      int g = (ks >= 35), ksr = ks - (g ? 35 : 0);
      int c = m * 16 + (l & 15), u = c >> 2, ty = c & 3, wrow = ty * 512 + u, koct = l >> 4;
      PK8 pk;
#pragma unroll
      for (int j = 0; j < 8; ++j) {
        int ke = ksr * 32 + koct * 8 + j; float x = 0.0f;
        if (ke < 1104) x = (ke < 592) ? Wih_att[(size_t)wrow * 592 + ke] : Whh_att[(size_t)wrow * 512 + (ke - 592)];
        unsigned short hi = bfh(x);
        pk.us[j] = g ? bfh(x - bf2f(hi)) : hi;
      }
      store_pk(WA2 + id * 8, pk);
    }
    // dec A-frags: groups [Ah(48); Al(48)], K=1536
    for (size_t id = (size_t)wg * NTH + tid; id < (size_t)128 * 96 * 64; id += (size_t)NWG * NTH) {
      int l = id & 63; size_t r = id >> 6; int ks = (int)(r % 96); int m = (int)(r / 96);
      int g = (ks >= 48), ksr = ks - (g ? 48 : 0);
      int c = m * 16 + (l & 15), u = c >> 2, ty = c & 3, wrow = ty * 512 + u, koct = l >> 4;
      PK8 pk;
#pragma unroll
      for (int j = 0; j < 8; ++j) {
        int ke = ksr * 32 + koct * 8 + j;
        float x = (ke < 1024) ? Wih_dec[(size_t)wrow * 1024 + ke] : Whh_dec[(size_t)wrow * 512 + (ke - 1024)];
        unsigned short hi = bfh(x);
        pk.us[j] = g ? bfh(x - bf2f(hi)) : hi;
      }
      store_pk(WD2 + id * 8, pk);
    }
    // conv A-frags: [32 mt][ks: hi{0,1} lo{2,3}][64][8]; K=62 pad 64
    for (size_t id = (size_t)wg * NTH + tid; id < (size_t)32 * 4 * 64; id += (size_t)NWG * NTH) {
      int l = id & 63; size_t r = id >> 6; int ks = (int)(r % 4); int mt = (int)(r / 4);
      int g = (ks >= 2), ks2 = ks & 1;
      int d = mt * 16 + (l & 15), koct = l >> 4;
      PK8 pk;
#pragma unroll
      for (int j = 0; j < 8; ++j) {
        int ke = ks2 * 32 + koct * 8 + j;
        float x = (ke < 62) ? Wloc[d * 62 + ke] : 0.0f;
        unsigned short hi = bfh(x);
        pk.us[j] = g ? bfh(x - bf2f(hi)) : hi;
      }
      store_pk(WL2 + id * 8, pk);
    }
    // m_proj: MP[b][t][d] = sum_k enc[b][t][k] * Wm[d][k]  (32x32 tiles)
    for (int tt = wg; tt < 8192; tt += NWG) {
      int b = tt >> 8, rr = tt & 255, d0 = (rr >> 4) * 32, t0 = (rr & 15) * 32;
      int ty2 = tid >> 5, tx = tid & 31;
      float acc = 0.0f;
      for (int kc = 0; kc < Dc; kc += 32) {
        __syncthreads();
        {
          int rr2 = tid >> 5, kk = tid & 31;
          sh.u.init.tw[rr2][kk] = Wm[(size_t)(d0 + rr2) * Dc + kc + kk];
          sh.u.init.ta[rr2][kk] = enc[((size_t)b * TENC + t0 + rr2) * Dc + kc + kk];
        }
        __syncthreads();
#pragma unroll 8
        for (int kk = 0; kk < 32; ++kk) acc += sh.u.init.tw[ty2][kk] * sh.u.init.ta[tx][kk];
      }
      stg_(MP + ((size_t)b * TENC + t0 + tx) * Dc + d0 + ty2, acc);
      __syncthreads();
    }
  }
  gbar();
  __builtin_amdgcn_fence(__ATOMIC_ACQUIRE, "agent");   // drop any stale L2 lines before plain reads
  // ---- load persistent LDS slices (WG = (b, tchunk), step-invariant) ----
  {
    const int b = wg & 31, t0 = (wg >> 5) * 64;
    for (int idx = tid; idx < 64 * 512; idx += NTH) {
      int t = idx >> 9, d = idx & 511;
      sh.mp[t][d] = bfh(ldg_(MP + ((size_t)b * TENC + t0 + t) * Dc + d));
      sh.en[t][d] = bfh(enc[((size_t)b * TENC + t0 + t) * Dc + d]);
    }
  }
  // ---- preload GG A-frags into persistent registers (kernel lifetime) ----
  const bool g_att = (wg < 128);
  const int gm = wg & 127;
  const int gP = g_att ? 35 : 48;
  const int gw = tid >> 6, gl = tid & 63;
  const short8* gXv = (const short8*)(g_att ? XSA : XSD);
  short8 a_h[3], a_l[3];
  {
    const int NK = g_att ? 70 : 96;
    const short8* Wv = (const short8*)(g_att ? WA2 : WD2);
#pragma unroll
    for (int t = 0; t < 3; ++t) {
      int i = gw + 16 * t;
      if (i < gP) {
        a_h[t] = Wv[((size_t)gm * NK + i) * 64 + gl];
        a_l[t] = Wv[((size_t)gm * NK + gP + i) * 64 + gl];
      }
    }
  }

  // ---- T1: conv MFMA + energy + softmax + ctx (uses LDS mp/en) ----
  auto T1 = [&](int n) {
    const int cur = n & 1, prv = 1 - cur;
    const int b = wg & 31, t0 = (wg >> 5) * 64;
    if (tid < 94) {
      int g = t0 - 15 + tid;
      bool ok = (g >= 0 && g < TENC);
      float rsp = 1.0f / ldg_(S + prv * 32 + b);
      float av = ok ? ldg_(Wb + (size_t)prv * Bc * TENC + b * TENC + g) * rsp : 0.0f;
      float ac = (ok ? ldg_(AC + (size_t)prv * Bc * TENC + b * TENC + g) : 0.0f) + av;
      sh.u.t1.ain[tid] = av; sh.u.t1.acin[tid] = ac;
    }
    if (tid >= 512) sh.u.t1.q[tid - 512] = ldg_(Q + (size_t)b * Dc + (tid - 512));
    if (tid >= 256 && tid < 512) {
      int d2 = tid - 256;
      sh.u.t1.v[d2] = v[d2];
      sh.u.t1.v[d2 + 256] = v[d2 + 256];
    }
    __syncthreads();
    if (tid < 64) stg_(AC + (size_t)cur * Bc * TENC + b * TENC + t0 + tid, sh.u.t1.acin[tid + 15]);
    // build ALL conv window B-frags: 1024 threads = 4nt x 4ks x 64l
    {
      int nt = tid >> 8, ks = (tid >> 6) & 3, l = tid & 63;
      int g = (ks >= 2), ks2 = ks & 1;
      int ttl = nt * 16 + (l & 15), koct = l >> 4;
      PK8 pk;
#pragma unroll
      for (int j = 0; j < 8; ++j) {
        int ke = ks2 * 32 + koct * 8 + j;
        float x = 0.0f;
        if (ke < 31) x = sh.u.t1.ain[ttl + ke];
        else if (ke < 62) x = sh.u.t1.acin[ttl + ke - 31];
        unsigned short hi = bfh(x);
        pk.us[j] = g ? bfh(x - bf2f(hi)) : hi;
      }
      *(short8*)&sh.u.t1.win[nt][ks][l][0] = pk.s8;
    }
    __syncthreads();
    // conv MFMA + energy
    {
      const int w = tid >> 6, l = tid & 63;
      const short8* WLv = (const short8*)WL2;
      short8 ah[2][2], al[2][2];
#pragma unroll
      for (int mi = 0; mi < 2; ++mi)
#pragma unroll
        for (int k2 = 0; k2 < 2; ++k2) {
          ah[mi][k2] = WLv[(((w * 2 + mi) * 4) + k2) * 64 + l];
          al[mi][k2] = WLv[(((w * 2 + mi) * 4) + 2 + k2) * 64 + l];
        }
      float ep[4] = {0.f, 0.f, 0.f, 0.f};
#pragma unroll 1
      for (int nt = 0; nt < 4; ++nt) {
        short8 bh0 = *(const short8*)&sh.u.t1.win[nt][0][l][0];
        short8 bh1 = *(const short8*)&sh.u.t1.win[nt][1][l][0];
        short8 bl0 = *(const short8*)&sh.u.t1.win[nt][2][l][0];
        short8 bl1 = *(const short8*)&sh.u.t1.win[nt][3][l][0];
#pragma unroll
        for (int mi = 0; mi < 2; ++mi) {
          f32x4 cc = {0.f, 0.f, 0.f, 0.f};
          cc = __builtin_amdgcn_mfma_f32_16x16x32_bf16(ah[mi][0], bh0, cc, 0, 0, 0);
          cc = __builtin_amdgcn_mfma_f32_16x16x32_bf16(ah[mi][1], bh1, cc, 0, 0, 0);
          cc = __builtin_amdgcn_mfma_f32_16x16x32_bf16(ah[mi][0], bl0, cc, 0, 0, 0);
          cc = __builtin_amdgcn_mfma_f32_16x16x32_bf16(ah[mi][1], bl1, cc, 0, 0, 0);
          cc = __builtin_amdgcn_mfma_f32_16x16x32_bf16(al[mi][0], bh0, cc, 0, 0, 0);
          cc = __builtin_amdgcn_mfma_f32_16x16x32_bf16(al[mi][1], bh1, cc, 0, 0, 0);
          int dbase = (w * 2 + mi) * 16 + (l >> 4) * 4;
          int tloc = nt * 16 + (l & 15);
          us4 mpu = *(const us4*)&sh.mp[tloc][dbase];
          f32x4 qv = *(const f32x4*)&sh.u.t1.q[dbase];
          f32x4 vv = *(const f32x4*)&sh.u.t1.v[dbase];
#pragma unroll
          for (int i = 0; i < 4; ++i) ep[nt] += vv[i] * tanhf2(cc[i] + qv[i] + bf2f(mpu[i]));
        }
      }
#pragma unroll
      for (int nt = 0; nt < 4; ++nt) {
        float e = ep[nt];
        e += __shfl_xor(e, 16);
        e += __shfl_xor(e, 32);
        if ((l >> 4) == 0) sh.u.t1.ered[w][nt * 16 + l] = e;
      }
    }
    __syncthreads();
    if (tid < 64) {
      float e = 0.0f;
#pragma unroll
      for (int w2 = 0; w2 < 16; ++w2) e += sh.u.t1.ered[w2][tid];
      float ex = __expf(e);
      stg_(Wb + (size_t)cur * Bc * TENC + b * TENC + t0 + tid, ex);
      sh.u.t1.we[tid] = ex;
      float sum = ex;
#pragma unroll
      for (int off = 32; off > 0; off >>= 1) sum += __shfl_down(sum, off, 64);
      if (tid == 0) atadd_(S + cur * 32 + b, sum);
    }
    __syncthreads();
    if (tid < 512) {
      float cp = 0.0f;
#pragma unroll 4
      for (int t2 = 0; t2 < 64; ++t2) cp += sh.u.t1.we[t2] * bf2f(sh.en[t2][tid]);
      atadd_(CT + (size_t)cur * Dc * Bc + tid * Bc + b, cp);
    }
  };

  // ---- XS: build B-frags (hi+lo) for both LSTM GEMMs; zero next accumulators ----
  auto XS = [&](int n, bool att_on) {
    const int cur = n & 1, nxt = 1 - cur;
    if (wg < 35) {                       // att ks = wg
      if (att_on && tid < 512) {
        int ks = wg, b = tid & 31, kp = tid >> 5;
        int kloc = kp * 2, koct = kloc >> 3, jj = kloc & 7;
        int l = koct * 16 + (b & 15), nt = b >> 4;
        float rs = 1.0f / ldg_(S + cur * 32 + b);
        unsigned short h2[2], l2v[2];
#pragma unroll
        for (int q2 = 0; q2 < 2; ++q2) {
          int ke = ks * 32 + kloc + q2; float x = 0.0f;
          if (ke < 1104) {
            if (ke < 80)       x = MT[(size_t)(n + 1) * MELc * Bc + ke * 32 + b];
            else if (ke < 592) x = ldg_(CT + (size_t)cur * Dc * Bc + (ke - 80) * 32 + b) * rs;
            else               x = ldg_(HA + (size_t)cur * Dc * Bc + (ke - 592) * 32 + b);
          }
          unsigned short hi = bfh(x);
          h2[q2] = hi; l2v[q2] = bfh(x - bf2f(hi));
        }
        unsigned ph = (unsigned)h2[0] | ((unsigned)h2[1] << 16);
        unsigned pl = (unsigned)l2v[0] | ((unsigned)l2v[1] << 16);
        stgu_((unsigned*)(XSA + ((size_t)(ks * 2 + nt) * 64 + l) * 8 + jj), ph);
        stgu_((unsigned*)(XSA + ((size_t)((35 + ks) * 2 + nt) * 64 + l) * 8 + jj), pl);
      }
    } else if (wg < 83) {                // dec ks = wg - 35
      if (n >= 0 && tid < 512) {
        int ks = wg - 35, b = tid & 31, kp = tid >> 5;
        int kloc = kp * 2, koct = kloc >> 3, jj = kloc & 7;
        int l = koct * 16 + (b & 15), nt = b >> 4;
        float rs = 1.0f / ldg_(S + cur * 32 + b);
        unsigned short h2[2], l2v[2];
#pragma unroll
        for (int q2 = 0; q2 < 2; ++q2) {
          int ke = ks * 32 + kloc + q2; float x;
          if (ke < 512)       x = ldg_(HA + (size_t)cur * Dc * Bc + ke * 32 + b);
          else if (ke < 1024) x = ldg_(CT + (size_t)cur * Dc * Bc + (ke - 512) * 32 + b) * rs;
          else                x = ldg_(HD + (size_t)nxt * Dc * Bc + (ke - 1024) * 32 + b);
          unsigned short hi = bfh(x);
          h2[q2] = hi; l2v[q2] = bfh(x - bf2f(hi));
        }
        unsigned ph = (unsigned)h2[0] | ((unsigned)h2[1] << 16);
        unsigned pl = (unsigned)l2v[0] | ((unsigned)l2v[1] << 16);
        stgu_((unsigned*)(XSD + ((size_t)(ks * 2 + nt) * 64 + l) * 8 + jj), ph);
        stgu_((unsigned*)(XSD + ((size_t)((48 + ks) * 2 + nt) * 64 + l) * 8 + jj), pl);
      }
    } else if (wg < 91) {
      for (int i = (wg - 83) * NTH + tid; i < Dc * Bc; i += 8 * NTH) stg_(CT + (size_t)nxt * Dc * Bc + i, 0.0f);
      if (wg == 83 && tid < Bc) stg_(S + nxt * 32 + tid, 0.0f);
    }
  };

  // ---- GG: att GEMM (WG 0..127) || dec GEMM (WG 128..255); A in registers ----
  auto GG = [&](int n, bool att_on) {
    const int cur = n & 1, nxt = 1 - cur;
    const bool active = g_att ? att_on : (n >= 0);
    // make XS's sc1-written B-frags visible to plain (cacheable) loads
    __builtin_amdgcn_fence(__ATOMIC_ACQUIRE, "agent");
    f32x4 acc0 = {0.f, 0.f, 0.f, 0.f}, acc1 = {0.f, 0.f, 0.f, 0.f};
    if (active) {
      short8 b0[3], b1[3], c0[3], c1[3];
#pragma unroll
      for (int t = 0; t < 3; ++t) {
        int i = gw + 16 * t;
        if (i < gP) {
          b0[t] = gXv[(size_t)(i * 2 + 0) * 64 + gl];
          b1[t] = gXv[(size_t)(i * 2 + 1) * 64 + gl];
          c0[t] = gXv[(size_t)((gP + i) * 2 + 0) * 64 + gl];
          c1[t] = gXv[(size_t)((gP + i) * 2 + 1) * 64 + gl];
        }
      }
#pragma unroll
      for (int t = 0; t < 3; ++t) {
        int i = gw + 16 * t;
        if (i < gP) {
          acc0 = __builtin_amdgcn_mfma_f32_16x16x32_bf16(a_h[t], b0[t], acc0, 0, 0, 0);
          acc0 = __builtin_amdgcn_mfma_f32_16x16x32_bf16(a_h[t], c0[t], acc0, 0, 0, 0);
          acc0 = __builtin_amdgcn_mfma_f32_16x16x32_bf16(a_l[t], b0[t], acc0, 0, 0, 0);
          acc1 = __builtin_amdgcn_mfma_f32_16x16x32_bf16(a_h[t], b1[t], acc1, 0, 0, 0);
          acc1 = __builtin_amdgcn_mfma_f32_16x16x32_bf16(a_h[t], c1[t], acc1, 0, 0, 0);
          acc1 = __builtin_amdgcn_mfma_f32_16x16x32_bf16(a_l[t], b1[t], acc1, 0, 0, 0);
        }
      }
    }
    if (active && gw < 8) { *(f32x4*)&sh.u.gg.red[gw][0][gl][0] = acc0; *(f32x4*)&sh.u.gg.red[gw][1][gl][0] = acc1; }
    __syncthreads();
    if (active && gw >= 8) {
      f32x4 r0 = *(const f32x4*)&sh.u.gg.red[gw - 8][0][gl][0];
      f32x4 r1 = *(const f32x4*)&sh.u.gg.red[gw - 8][1][gl][0];
      *(f32x4*)&sh.u.gg.red[gw - 8][0][gl][0] = r0 + acc0;
      *(f32x4*)&sh.u.gg.red[gw - 8][1][gl][0] = r1 + acc1;
    }
    __syncthreads();
    if (active && tid < 128) {
      int nt = tid >> 6, l2 = tid & 63;
      float g4[4] = {0.f, 0.f, 0.f, 0.f};
#pragma unroll
      for (int w2 = 0; w2 < 8; ++w2) {
        f32x4 r = *(const f32x4*)&sh.u.gg.red[w2][nt][l2][0];
        g4[0] += r[0]; g4[1] += r[1]; g4[2] += r[2]; g4[3] += r[3];
      }
      int u = gm * 4 + (l2 >> 4), b = nt * 16 + (l2 & 15);
      const float* Bv = g_att ? BA : BD;
#pragma unroll
      for (int ty = 0; ty < 4; ++ty) g4[ty] += ldg_(Bv + u * 4 + ty);
      float* Cst = g_att ? CA : CD;
      float co = ldg_(Cst + u * 32 + b);
      float cn = sigf(g4[1]) * co + sigf(g4[0]) * tanhf2(g4[2]);
      stg_(Cst + u * 32 + b, cn);
      float h = sigf(g4[3]) * tanhf2(cn);
      stg_((g_att ? (HA + (size_t)nxt * Dc * Bc) : (HD + (size_t)cur * Dc * Bc)) + u * 32 + b, h);
    }
  };

  // ---- QM: q projection + mel/stop outputs ----
  auto QM = [&](int n) {
    const int cur = n & 1, nxt = 1 - cur;
    if (wg < 64) {
      if (n < TDECc - 1) {
        int b = wg >> 1;
        for (int k = tid; k < Dc; k += NTH) sh.u.qm.h[k] = ldg_(HA + (size_t)nxt * Dc * Bc + k * Bc + b);
        __syncthreads();
        int ks = tid >> 8, dl = tid & 255, d = (wg & 1) * 256 + dl;
        float acc = 0.0f;
        const int k0 = ks * 128, k1 = k0 + 128;
#pragma unroll 4
        for (int k = k0; k < k1; ++k) acc += WQT[(size_t)k * Dc + d] * sh.u.qm.h[k];
        sh.u.qm.part[dl][ks] = acc;
        __syncthreads();
        if (tid < 256)
          stg_(Q + (size_t)b * Dc + (wg & 1) * 256 + tid,
               sh.u.qm.part[tid][0] + sh.u.qm.part[tid][1] + sh.u.qm.part[tid][2] + sh.u.qm.part[tid][3]);
      }
    } else if (wg < 74) {
      if (n >= 0) {
        int b2 = tid & 31, mq = tid >> 5, ml = mq & 7, ks = mq >> 3;
        int m = (wg - 64) * 8 + ml;
        float acc = (ks == 0) ? bmel[m] : 0.0f;
        const int k0 = ks * 128, k1 = k0 + 128;
#pragma unroll 4
        for (int k = k0; k < k1; ++k) acc += WMT[(size_t)k * MELc + m] * ldg_(HD + (size_t)cur * Dc * Bc + k * Bc + b2);
        sh.u.qm.part[(ml << 5) | b2][ks] = acc;
        __syncthreads();
        if (tid < 256) {
          int mm = (wg - 64) * 8 + (tid >> 5), bb = tid & 31;
          stg_(out + (size_t)bb * TDECc * MELc + (size_t)n * MELc + mm,
               sh.u.qm.part[tid][0] + sh.u.qm.part[tid][1] + sh.u.qm.part[tid][2] + sh.u.qm.part[tid][3]);
        }
      }
    } else if (wg == 74) {
      if (n >= 0) {
        int b2 = tid & 31, ks = tid >> 5;
        float acc = (ks == 0) ? bstop[0] : 0.0f;
        const int k0 = ks * 16, k1 = k0 + 16;
#pragma unroll 4
        for (int k = k0; k < k1; ++k) acc += Wstop[k] * ldg_(HD + (size_t)cur * Dc * Bc + k * Bc + b2);
        sh.u.qm.sp[ks][b2] = acc;
        __syncthreads();
        if (tid < 32) {
          float s2 = 0.0f;
#pragma unroll
          for (int i = 0; i < 32; ++i) s2 += sh.u.qm.sp[i][tid];
          stg_(out + (size_t)Bc * TDECc * MELc + (size_t)tid * TDECc + n, s2);
        }
      }
    }
  };

  // ================= schedule =================
  gbar();
  XS(-1, true);  gbar();   // att x for step 0 (mel0, ctx=0, h=0)
  GG(-1, true);  gbar();   // h_att(0)
  QM(-1);        gbar();   // q(0)
#pragma unroll 1
  for (int n = 0; n < TDECc; ++n) {
    bool att_on = (n < TDECc - 1);
    T1(n);           gbar();
    XS(n, att_on);   gbar();
    GG(n, att_on);   gbar();
    QM(n);           gbar();
  }
}

extern "C" void kernel_launch(void* const* d_in, const int* in_sizes, int n_in,
                              void* d_out, int out_size, void* d_ws, size_t ws_size,
                              hipStream_t stream) {
  (void)in_sizes; (void)n_in; (void)out_size; (void)ws_size;
  const float* enc     = (const float*)d_in[0];
  const float* mel_in  = (const float*)d_in[1];
  const float* Wih_att = (const float*)d_in[2];
  const float* Whh_att = (const float*)d_in[3];
  const float* b_att   = (const float*)d_in[4];
  const float* Wih_dec = (const float*)d_in[5];
  const float* Whh_dec = (const float*)d_in[6];
  const float* b_dec   = (const float*)d_in[7];
  const float* Wq      = (const float*)d_in[8];
  const float* Wm      = (const float*)d_in[9];
  const float* Wloc    = (const float*)d_in[10];
  const float* v       = (const float*)d_in[11];
  const float* Wmel    = (const float*)d_in[12];
  const float* bmel    = (const float*)d_in[13];
  const float* Wstop   = (const float*)d_in[14];
  const float* bstop   = (const float*)d_in[15];
  float* out = (float*)d_out;
  float* ws  = (float*)d_ws;

  hipMemsetAsync(d_ws, 0, ZERO_END * sizeof(float), stream);

  const int lds_bytes = (int)sizeof(Lds);   // ~158.7 KB dynamic LDS
  (void)hipFuncSetAttribute((const void*)decoder_persist,
                            hipFuncAttributeMaxDynamicSharedMemorySize, lds_bytes);

  void* args[] = { &enc, &mel_in, &Wih_att, &Whh_att, &b_att, &Wih_dec, &Whh_dec, &b_dec,
                   &Wq, &Wm, &Wloc, &v, &Wmel, &bmel, &Wstop, &bstop, &out, &ws };
  hipLaunchCooperativeKernel((void*)decoder_persist, dim3(NWG), dim3(NTH), args,
                             (size_t)lds_bytes, stream);
}